// Round 8
// baseline (25.645 us; speedup 1.0000x reference)
//
#include <hip/hip_runtime.h>

#define KP 137
#define SS 512
#define BB 128
#define STRIP 4
#define NSTRIP (SS / STRIP)          // 128 strips per batch
#define NBLK (BB * NSTRIP)           // 16384 one-wave blocks

// Lane -> keypoint mapping (3 overlapped sub-batches; every bone pair is
// intra-sub-batch): a = kp lane (0..63), b = kp 63+lane (63..126),
// c = kp 126+lanec, lanec = min(lane,10) (lanes>10 load kp136 garbage, masked).
// Pose counted once: a all lanes, b lanes>=1, c lanes 1..10.
// Bone pairs: a lane<63 (k 0..62), b lane<63 (k 63..125), c lane<10 (k 126..135).

struct Pay {                        // one row's payload: pred row s, target row s+1
    float2 pa, pb, pc;
    float t1xa, t1xb, t1xc, t1ya, t1yb, t1yc;
};

__device__ __forceinline__ Pay loadrow(const float2* __restrict__ pp,
                                       const float* __restrict__ txp,
                                       const float* __restrict__ typ,
                                       int s, int lane, int lanec) {
    Pay P;
    const float2* pr = pp + (size_t)s * KP;
    P.pa = pr[lane];
    P.pb = pr[63 + lane];
    P.pc = pr[126 + lanec];
    const int sn = (s + 1 < SS) ? s + 1 : SS - 1;       // clamp; garbage masked
    const float* r = txp + sn * KP;
    const float* q = typ + sn * KP;
    P.t1xa = r[lane]; P.t1xb = r[63 + lane]; P.t1xc = r[126 + lanec];
    P.t1ya = q[lane]; P.t1yb = q[63 + lane]; P.t1yc = q[126 + lanec];
    return P;
}

__global__ __launch_bounds__(64) void t2p_main(
    const float* __restrict__ pred,      // [B,S,2K]
    const float* __restrict__ tgt,       // [B,2,S,K]
    const int*   __restrict__ tlen,      // [B]
    float2* __restrict__ partials)       // [NBLK]
{
    const int lane  = threadIdx.x;           // one wave per block
    const int lanec = (lane <= 10) ? lane : 10;
    const int w     = blockIdx.x;
    const int b     = w >> 7;                // NSTRIP = 128
    const int s0    = (w & (NSTRIP - 1)) * STRIP;
    const int len   = tlen[b];

    float pose = 0.f, bone = 0.f;

    if (s0 < len) {
        const int send = (len < s0 + STRIP) ? len : (s0 + STRIP);
        const float* txp = tgt + (size_t)(2 * b) * SS * KP;   // x plane (SGPR base)
        const float* typ = txp + (size_t)SS * KP;             // y plane
        const float2* pp = (const float2*)(pred + (size_t)b * SS * (2 * KP));

        // prologue: same-row target (row s0) + payload for row s0
        float t0xa, t0xb, t0xc, t0ya, t0yb, t0yc;
        {
            const float* r = txp + s0 * KP;
            const float* q = typ + s0 * KP;
            t0xa = r[lane]; t0xb = r[63 + lane]; t0xc = r[126 + lanec];
            t0ya = q[lane]; t0yb = q[63 + lane]; t0yc = q[126 + lanec];
        }
        Pay cur = loadrow(pp, txp, typ, s0, lane, lanec);

        for (int s = s0; s < send; ++s) {
            // prefetch next row's payload (branch-free, clamped) BEFORE compute
            const int sp = (s + 1 < SS) ? s + 1 : SS - 1;
            Pay nxt = loadrow(pp, txp, typ, sp, lane, lanec);

            // ---- pose: pred row s vs target row s+1 (cur.t1) ----
            if (s < len - 1) {               // wave-uniform
                float acc = fabsf(cur.pa.x - cur.t1xa) + fabsf(cur.pa.y - cur.t1ya);
                acc += (lane >= 1)
                     ? fabsf(cur.pb.x - cur.t1xb) + fabsf(cur.pb.y - cur.t1yb) : 0.f;
                acc += (lane >= 1 && lane <= 10)
                     ? fabsf(cur.pc.x - cur.t1xc) + fabsf(cur.pc.y - cur.t1yc) : 0.f;
                pose += acc;
            }

            // ---- bone: e = pred - target(row s), chain diff via lane shift ----
            {
                float exa = cur.pa.x - t0xa, eya = cur.pa.y - t0ya;
                float exb = cur.pb.x - t0xb, eyb = cur.pb.y - t0yb;
                float exc = cur.pc.x - t0xc, eyc = cur.pc.y - t0yc;
                float nxa = __shfl_down(exa, 1, 64), nya = __shfl_down(eya, 1, 64);
                float nxb = __shfl_down(exb, 1, 64), nyb = __shfl_down(eyb, 1, 64);
                float nxc = __shfl_down(exc, 1, 64), nyc = __shfl_down(eyc, 1, 64);
                float acc = 0.f;
                if (lane < 63) {
                    float dx = nxa - exa, dy = nya - eya; acc += dx * dx + dy * dy;
                    float ex = nxb - exb, ey = nyb - eyb; acc += ex * ex + ey * ey;
                }
                if (lane < 10) {
                    float dx = nxc - exc, dy = nyc - eyc; acc += dx * dx + dy * dy;
                }
                bone += acc;
            }

            // roll: cur's target row s+1 becomes next iteration's same-row target
            t0xa = cur.t1xa; t0xb = cur.t1xb; t0xc = cur.t1xc;
            t0ya = cur.t1ya; t0yb = cur.t1yb; t0yc = cur.t1yc;
            cur = nxt;
        }
    }

    // wave reduce; no LDS, no barrier
    for (int off = 32; off > 0; off >>= 1) {
        pose += __shfl_down(pose, off, 64);
        bone += __shfl_down(bone, off, 64);
    }
    if (lane == 0) partials[w] = make_float2(pose, bone);
}

__global__ __launch_bounds__(1024) void t2p_final(
    const float2* __restrict__ partials,
    const int* __restrict__ tlen,
    float* __restrict__ out)
{
    const int t = threadIdx.x;
    float ps = 0.f, bs = 0.f;
    #pragma unroll
    for (int i = 0; i < NBLK / 1024; ++i) {      // 16 each
        float2 v = partials[t + i * 1024];
        ps += v.x; bs += v.y;
    }
    float pc = 0.f, mc = 0.f;
    if (t < BB) {
        int L = tlen[t];
        pc = (float)(L - 1);   // sum(pose_mask)
        mc = (float)L;         // sum(mask)
    }
    for (int off = 32; off > 0; off >>= 1) {
        ps += __shfl_down(ps, off, 64);
        bs += __shfl_down(bs, off, 64);
        pc += __shfl_down(pc, off, 64);
        mc += __shfl_down(mc, off, 64);
    }
    __shared__ float4 wsum[16];
    if ((t & 63) == 0) wsum[t >> 6] = make_float4(ps, bs, pc, mc);
    __syncthreads();
    if (t == 0) {
        float4 a = wsum[0];
        #pragma unroll
        for (int i = 1; i < 16; ++i) {
            a.x += wsum[i].x; a.y += wsum[i].y;
            a.z += wsum[i].z; a.w += wsum[i].w;
        }
        float pose_loss = a.x / (274.f * a.z);
        float bone_loss = (a.y * 0.5f) / ((136.f + 1e-8f) * a.w);
        out[0] = pose_loss + 0.1f * bone_loss;   // POSE_W=1, BONE_W=0.1
        out[1] = pose_loss;
        out[2] = bone_loss;
    }
}

extern "C" void kernel_launch(void* const* d_in, const int* in_sizes, int n_in,
                              void* d_out, int out_size, void* d_ws, size_t ws_size,
                              hipStream_t stream) {
    const float* pred = (const float*)d_in[0];   // [128,512,274] f32
    const float* tgt  = (const float*)d_in[1];   // [128,2,512,137] f32
    const int*   tlen = (const int*)d_in[2];     // [128] i32
    float* out = (float*)d_out;
    float2* partials = (float2*)d_ws;            // 16384 * 8 B = 128 KB

    t2p_main<<<NBLK, 64, 0, stream>>>(pred, tgt, tlen, partials);
    t2p_final<<<1, 1024, 0, stream>>>(partials, tlen, out);
}